// Round 8
// baseline (15.625 us; speedup 1.0000x reference)
//
#include <hip/hip_runtime.h>
#include <hip/hip_fp16.h>

// LocalAttention: B=1, H=8, S=2048, D=64, window +/-64 (129 positions), fp32 io.
// Two-pass design.
//  Pass 1 (convert_kv): k,v fp32 -> f16 in d_ws.
//    K16: per head 2176 rows (64 zero-guards each side), row = 128 B with 16B-chunk
//         swizzle (chunk c stored at c ^ (g&7)).
//    VT16: per head [64 dims][2176 rows] f16, per-dim row = 4352 B, chunk index
//         (gg>>3) with low-3 XOR (d&7), element offset (gg&7)*2  — byte-identical
//         to the verified R6 LDS VtB image for any qbase multiple of 64.
//  Pass 2 (local_attn_main): R6 split-k MFMA structure; staging is just
//    6x global_load_lds(16B)/thread from the pre-converted workspace.
// Fallback: R6 self-staging kernel if ws_size too small.

#define SEQ 2048
#define NH 8
#define QB 64
#define ROWS 192
#define PSTR 40          // P strip stride in halfs (80 B)

#define KHEAD 278528     // 2176 rows * 128 B
#define VOFF  2228224    // 8 * KHEAD
#define VROW  4352       // 2176 * 2 B per dim-row
#define WSNEED (VOFF + 8 * 278528)

typedef _Float16 f16x8 __attribute__((ext_vector_type(8)));
typedef float    f32x4 __attribute__((ext_vector_type(4)));

#define GLOAD_LDS16(gsrc, ldst)                                              \
    __builtin_amdgcn_global_load_lds(                                        \
        (const __attribute__((address_space(1))) unsigned int*)(gsrc),       \
        (__attribute__((address_space(3))) unsigned int*)(ldst), 16, 0, 0)

// ---------------------------------------------------------------- pass 1
__global__ __launch_bounds__(256) void convert_kv(
    const float* __restrict__ k,
    const float* __restrict__ v,
    unsigned char* __restrict__ ws)
{
    const int b   = blockIdx.x;
    const int tid = threadIdx.x;
    if (b < 544) {
        // K: h = b&7 (XCD affinity), 32 storage rows per block, 8 chunk-threads/row
        const int h      = b & 7;
        const int rowblk = b >> 3;                  // 0..67
        const int gg     = rowblk * 32 + (tid >> 3); // storage row 0..2175
        const int c      = tid & 7;                  // 16B chunk (8 dims)
        const int g      = gg - 64;
        union { _Float16 h8[8]; uint4 u; } pk;
        if (g >= 0 && g < SEQ) {
            const float* kr = k + ((size_t)h * SEQ + g) * 64 + c * 8;
            float4 a = *(const float4*)kr;
            float4 bb = *(const float4*)(kr + 4);
            pk.h8[0] = (_Float16)a.x;  pk.h8[1] = (_Float16)a.y;
            pk.h8[2] = (_Float16)a.z;  pk.h8[3] = (_Float16)a.w;
            pk.h8[4] = (_Float16)bb.x; pk.h8[5] = (_Float16)bb.y;
            pk.h8[6] = (_Float16)bb.z; pk.h8[7] = (_Float16)bb.w;
        } else {
            pk.u = make_uint4(0, 0, 0, 0);
        }
        *(uint4*)(ws + (size_t)h * KHEAD + (size_t)gg * 128
                     + ((c ^ (gg & 7)) << 4)) = pk.u;
    } else {
        // V^T: h = b2&7, 16 storage rows x 64 dims per block
        const int b2  = b - 544;
        const int h   = b2 & 7;
        const int grp = b2 >> 3;                    // 0..135
        const int d   = tid & 63;
        const int gg0 = grp * 16 + (tid >> 6) * 4;  // storage row group (mult of 4)
        const int g0  = gg0 - 64;
        union { _Float16 h4[4]; uint2 u; } pv;
        #pragma unroll
        for (int i = 0; i < 4; ++i) {
            const int g = g0 + i;
            const float val = (g >= 0 && g < SEQ)
                ? v[((size_t)h * SEQ + g) * 64 + d] : 0.f;
            pv.h4[i] = (_Float16)val;
        }
        const int chunk = (gg0 >> 3) ^ (d & 7);     // low-3 XOR (d&7 < 8)
        *(uint2*)(ws + VOFF + (size_t)h * KHEAD + (size_t)d * VROW
                     + (size_t)chunk * 16 + (gg0 & 7) * 2) = pv.u;
    }
}

// ---------------------------------------------------------------- pass 2
__global__ __launch_bounds__(512) void local_attn_main(
    const float* __restrict__ q,
    const unsigned char* __restrict__ ws,
    float* __restrict__ out)
{
    __shared__ __align__(16) _Float16      Kl[ROWS * 64];     // 24576 B, stride 128 B
    __shared__ __align__(16) unsigned char VtB[64 * 384];     // 24576 B
    __shared__ __align__(16) _Float16      Pm[8][16 * PSTR];  // 10240 B
    __shared__ __align__(16) float         Cmb[4][64][20];    // 20480 B

    const int tid  = threadIdx.x;
    const int lane = tid & 63;
    const int w    = tid >> 6;           // 0..7
    const int t    = w & 3;              // q-tile 0..3
    const int half = w >> 2;             // 0: chunks 0-2, 1: chunks 3-5
    const int l15  = lane & 15;
    const int l4   = lane >> 4;
    const int bx   = blockIdx.x;
    const int h     = bx & 7;            // head == XCD (round-robin dispatch)
    const int qbase = (bx >> 3) * QB;

    const float* qh = q + (size_t)h * SEQ * 64;

    // ---- Q A-fragments from global (1/sqrt(64)=0.125 folded in)
    const float* qrow = qh + (size_t)(qbase + t * 16 + l15) * 64 + l4 * 8;
    float4 q0 = *(const float4*)(qrow);
    float4 q1 = *(const float4*)(qrow + 4);
    float4 q2 = *(const float4*)(qrow + 32);
    float4 q3 = *(const float4*)(qrow + 36);

    // ---- async staging: 3x K + 3x V global_load_lds(16B) per thread
    {
        const unsigned char* kws = ws + (size_t)h * KHEAD + (size_t)qbase * 128;
        const unsigned char* vws = ws + VOFF + (size_t)h * KHEAD;
        const int vseg = qbase * 2;      // segment start byte within each dim-row
        #pragma unroll
        for (int j = 0; j < 3; ++j) {
            const int off = (w + j * 8) * 1024;
            GLOAD_LDS16(kws + off + lane * 16, ((unsigned char*)Kl) + off);
            const unsigned x = off + lane * 16;
            const unsigned n = x >> 4;
            const unsigned d = n / 24u;              // 24 chunks per dim-row
            const unsigned rb = (n - d * 24u) << 4;
            GLOAD_LDS16(vws + (size_t)d * VROW + vseg + rb,
                        ((unsigned char*)VtB) + off);
        }
    }

    union uf { f16x8 v; _Float16 hh[8]; };
    uf A0, A1;
    A0.hh[0] = (_Float16)(q0.x * 0.125f); A0.hh[1] = (_Float16)(q0.y * 0.125f);
    A0.hh[2] = (_Float16)(q0.z * 0.125f); A0.hh[3] = (_Float16)(q0.w * 0.125f);
    A0.hh[4] = (_Float16)(q1.x * 0.125f); A0.hh[5] = (_Float16)(q1.y * 0.125f);
    A0.hh[6] = (_Float16)(q1.z * 0.125f); A0.hh[7] = (_Float16)(q1.w * 0.125f);
    A1.hh[0] = (_Float16)(q2.x * 0.125f); A1.hh[1] = (_Float16)(q2.y * 0.125f);
    A1.hh[2] = (_Float16)(q2.z * 0.125f); A1.hh[3] = (_Float16)(q2.w * 0.125f);
    A1.hh[4] = (_Float16)(q3.x * 0.125f); A1.hh[5] = (_Float16)(q3.y * 0.125f);
    A1.hh[6] = (_Float16)(q3.z * 0.125f); A1.hh[7] = (_Float16)(q3.w * 0.125f);

    asm volatile("s_waitcnt vmcnt(0)" ::: "memory");
    __syncthreads();

    // ---- main loop: wave-private, 3 chunks per wave
    _Float16* Pw = Pm[w];
    float rsum[4] = {0.f, 0.f, 0.f, 0.f};
    f32x4 o[4];
    #pragma unroll
    for (int dt = 0; dt < 4; ++dt) o[dt] = (f32x4){0.f, 0.f, 0.f, 0.f};

    #pragma unroll
    for (int c = 0; c < 3; ++c) {
        const int r0 = (half * 3 + c) * 32;

        // QK^T for this 32-row chunk: 2 tiles
        #pragma unroll
        for (int t2 = 0; t2 < 2; ++t2) {
            const int r = r0 + t2 * 16 + l15;          // staged row (C col)
            f16x8 b0 = *(const f16x8*)&Kl[r * 64 + (( l4      ^ (r & 7)) << 3)];
            f16x8 b1 = *(const f16x8*)&Kl[r * 64 + (((l4 + 4) ^ (r & 7)) << 3)];
            f32x4 cacc = {0.f, 0.f, 0.f, 0.f};
            cacc = __builtin_amdgcn_mfma_f32_16x16x32_f16(A0.v, b0, cacc, 0, 0, 0);
            cacc = __builtin_amdgcn_mfma_f32_16x16x32_f16(A1.v, b1, cacc, 0, 0, 0);
            const int g  = qbase - 64 + r;
            const bool gv = (g >= 0) & (g < SEQ);
            #pragma unroll
            for (int j = 0; j < 4; ++j) {
                const int qg = qbase + t * 16 + l4 * 4 + j;   // global query (C row)
                const bool valid = gv && (g >= qg - 64) && (g <= qg + 64);
                const float e = valid ? __expf(cacc[j]) : 0.f;
                rsum[j] += e;
                Pw[(l4 * 4 + j) * PSTR + t2 * 16 + l15] = (_Float16)e;
            }
        }

        // same-wave DS order; drain so P reads see the writes
        asm volatile("s_waitcnt lgkmcnt(0)" ::: "memory");

        // PV: A = P chunk (lane l15 = query), B = V^T (lane l15 = dim)
        f16x8 a = *(const f16x8*)&Pw[l15 * PSTR + l4 * 8];
        #pragma unroll
        for (int dt = 0; dt < 4; ++dt) {
            const int dim = dt * 16 + l15;
            const int u   = ((r0 + l4 * 8) >> 3) ^ (dim & 7);
            f16x8 bb = *(const f16x8*)&VtB[dim * 384 + (u << 4)];
            o[dt] = __builtin_amdgcn_mfma_f32_16x16x32_f16(a, bb, o[dt], 0, 0, 0);
        }
    }

    // ---- split-k combine: half-1 waves publish partials; half-0 waves merge
    if (half == 1) {
        #pragma unroll
        for (int dt = 0; dt < 4; ++dt)
            *(f32x4*)&Cmb[t][lane][dt * 4] = o[dt];
        f32x4 pr = {rsum[0], rsum[1], rsum[2], rsum[3]};
        *(f32x4*)&Cmb[t][lane][16] = pr;
    }
    __syncthreads();
    if (half == 0) {
        #pragma unroll
        for (int dt = 0; dt < 4; ++dt) {
            f32x4 p = *(const f32x4*)&Cmb[t][lane][dt * 4];
            o[dt] += p;
        }
        f32x4 pr = *(const f32x4*)&Cmb[t][lane][16];

        #pragma unroll
        for (int j = 0; j < 4; ++j) {
            float l = rsum[j] + pr[j];
            l += __shfl_xor(l, 1, 64);
            l += __shfl_xor(l, 2, 64);
            l += __shfl_xor(l, 4, 64);
            l += __shfl_xor(l, 8, 64);
            const float inv = 1.0f / l;
            const int qg = qbase + t * 16 + l4 * 4 + j;
            #pragma unroll
            for (int dt = 0; dt < 4; ++dt)
                out[((size_t)h * SEQ + qg) * 64 + dt * 16 + l15] = o[dt][j] * inv;
        }
    }
}

// ---------------------------------------------------------------- fallback (R6)
__global__ __launch_bounds__(512) void local_attn_fb(
    const float* __restrict__ q,
    const float* __restrict__ k,
    const float* __restrict__ v,
    float* __restrict__ out)
{
    __shared__ __align__(16) _Float16      Kl[ROWS * 72];
    __shared__ __align__(16) unsigned char VtB[64 * 384];
    __shared__ __align__(16) _Float16      Pm[8][16 * PSTR];
    __shared__ __align__(16) float         Cmb[4][64][20];

    const int tid  = threadIdx.x;
    const int lane = tid & 63;
    const int w    = tid >> 6;
    const int t    = w & 3;
    const int half = w >> 2;
    const int l15  = lane & 15;
    const int l4   = lane >> 4;
    const int bx   = blockIdx.x;
    const int h     = bx & 7;
    const int qbase = (bx >> 3) * QB;

    const float* kh = k + (size_t)h * SEQ * 64;
    const float* vh = v + (size_t)h * SEQ * 64;
    const float* qh = q + (size_t)h * SEQ * 64;

    const float* qrow = qh + (size_t)(qbase + t * 16 + l15) * 64 + l4 * 8;
    float4 q0 = *(const float4*)(qrow);
    float4 q1 = *(const float4*)(qrow + 4);
    float4 q2 = *(const float4*)(qrow + 32);
    float4 q3 = *(const float4*)(qrow + 36);
    union uf { f16x8 v; _Float16 hh[8]; };
    uf A0, A1;
    A0.hh[0] = (_Float16)(q0.x * 0.125f); A0.hh[1] = (_Float16)(q0.y * 0.125f);
    A0.hh[2] = (_Float16)(q0.z * 0.125f); A0.hh[3] = (_Float16)(q0.w * 0.125f);
    A0.hh[4] = (_Float16)(q1.x * 0.125f); A0.hh[5] = (_Float16)(q1.y * 0.125f);
    A0.hh[6] = (_Float16)(q1.z * 0.125f); A0.hh[7] = (_Float16)(q1.w * 0.125f);
    A1.hh[0] = (_Float16)(q2.x * 0.125f); A1.hh[1] = (_Float16)(q2.y * 0.125f);
    A1.hh[2] = (_Float16)(q2.z * 0.125f); A1.hh[3] = (_Float16)(q2.w * 0.125f);
    A1.hh[4] = (_Float16)(q3.x * 0.125f); A1.hh[5] = (_Float16)(q3.y * 0.125f);
    A1.hh[6] = (_Float16)(q3.z * 0.125f); A1.hh[7] = (_Float16)(q3.w * 0.125f);

    {
        const int d4  = (tid & 15) << 2;
        const int lr0 = tid >> 4;
        #pragma unroll
        for (int it = 0; it < 6; ++it) {
            const int lr = lr0 + it * 32;
            const int g  = qbase - 64 + lr;
            float4 kv4 = make_float4(0.f, 0.f, 0.f, 0.f);
            float4 vv4 = make_float4(0.f, 0.f, 0.f, 0.f);
            if (g >= 0 && g < SEQ) {
                kv4 = *(const float4*)(kh + (size_t)g * 64 + d4);
                vv4 = *(const float4*)(vh + (size_t)g * 64 + d4);
            }
            union { _Float16 hh[4]; ushort4 u; } pk;
            pk.hh[0] = (_Float16)kv4.x; pk.hh[1] = (_Float16)kv4.y;
            pk.hh[2] = (_Float16)kv4.z; pk.hh[3] = (_Float16)kv4.w;
            *(ushort4*)&Kl[lr * 72 + d4] = pk.u;
            float vs[4] = {vv4.x, vv4.y, vv4.z, vv4.w};
            #pragma unroll
            for (int i2 = 0; i2 < 4; ++i2) {
                int d = d4 + i2;
                int u = (lr >> 3) ^ (d & 7);
                *(_Float16*)&VtB[d * 384 + (u << 4) + (lr & 7) * 2] = (_Float16)vs[i2];
            }
        }
    }
    __syncthreads();

    _Float16* Pw = Pm[w];
    float rsum[4] = {0.f, 0.f, 0.f, 0.f};
    f32x4 o[4];
    #pragma unroll
    for (int dt = 0; dt < 4; ++dt) o[dt] = (f32x4){0.f, 0.f, 0.f, 0.f};

    #pragma unroll
    for (int c = 0; c < 3; ++c) {
        const int r0 = (half * 3 + c) * 32;
        #pragma unroll
        for (int t2 = 0; t2 < 2; ++t2) {
            const int r = r0 + t2 * 16 + l15;
            f16x8 b0 = *(const f16x8*)&Kl[r * 72 + l4 * 8];
            f16x8 b1 = *(const f16x8*)&Kl[r * 72 + 32 + l4 * 8];
            f32x4 cacc = {0.f, 0.f, 0.f, 0.f};
            cacc = __builtin_amdgcn_mfma_f32_16x16x32_f16(A0.v, b0, cacc, 0, 0, 0);
            cacc = __builtin_amdgcn_mfma_f32_16x16x32_f16(A1.v, b1, cacc, 0, 0, 0);
            const int g  = qbase - 64 + r;
            const bool gv = (g >= 0) & (g < SEQ);
            #pragma unroll
            for (int j = 0; j < 4; ++j) {
                const int qg = qbase + t * 16 + l4 * 4 + j;
                const bool valid = gv && (g >= qg - 64) && (g <= qg + 64);
                const float e = valid ? __expf(cacc[j]) : 0.f;
                rsum[j] += e;
                Pw[(l4 * 4 + j) * PSTR + t2 * 16 + l15] = (_Float16)e;
            }
        }
        asm volatile("s_waitcnt lgkmcnt(0)" ::: "memory");
        f16x8 a = *(const f16x8*)&Pw[l15 * PSTR + l4 * 8];
        #pragma unroll
        for (int dt = 0; dt < 4; ++dt) {
            const int dim = dt * 16 + l15;
            const int u   = ((r0 + l4 * 8) >> 3) ^ (dim & 7);
            f16x8 bb = *(const f16x8*)&VtB[dim * 384 + (u << 4)];
            o[dt] = __builtin_amdgcn_mfma_f32_16x16x32_f16(a, bb, o[dt], 0, 0, 0);
        }
    }

    if (half == 1) {
        #pragma unroll
        for (int dt = 0; dt < 4; ++dt)
            *(f32x4*)&Cmb[t][lane][dt * 4] = o[dt];
        f32x4 pr = {rsum[0], rsum[1], rsum[2], rsum[3]};
        *(f32x4*)&Cmb[t][lane][16] = pr;
    }
    __syncthreads();
    if (half == 0) {
        #pragma unroll
        for (int dt = 0; dt < 4; ++dt) {
            f32x4 p = *(const f32x4*)&Cmb[t][lane][dt * 4];
            o[dt] += p;
        }
        f32x4 pr = *(const f32x4*)&Cmb[t][lane][16];
        #pragma unroll
        for (int j = 0; j < 4; ++j) {
            float l = rsum[j] + pr[j];
            l += __shfl_xor(l, 1, 64);
            l += __shfl_xor(l, 2, 64);
            l += __shfl_xor(l, 4, 64);
            l += __shfl_xor(l, 8, 64);
            const float inv = 1.0f / l;
            const int qg = qbase + t * 16 + l4 * 4 + j;
            #pragma unroll
            for (int dt = 0; dt < 4; ++dt)
                out[((size_t)h * SEQ + qg) * 64 + dt * 16 + l15] = o[dt][j] * inv;
        }
    }
}

extern "C" void kernel_launch(void* const* d_in, const int* in_sizes, int n_in,
                              void* d_out, int out_size, void* d_ws, size_t ws_size,
                              hipStream_t stream)
{
    const float* q = (const float*)d_in[0];
    const float* k = (const float*)d_in[1];
    const float* v = (const float*)d_in[2];
    float* out = (float*)d_out;

    if (ws_size >= (size_t)WSNEED) {
        convert_kv<<<1632, 256, 0, stream>>>(k, v, (unsigned char*)d_ws);
        local_attn_main<<<256, 512, 0, stream>>>(q, (const unsigned char*)d_ws, out);
    } else {
        local_attn_fb<<<256, 512, 0, stream>>>(q, k, v, out);
    }
}

// Round 9
// 12.655 us; speedup vs baseline: 1.2348x; 1.2348x over previous
//
#include <hip/hip_runtime.h>
#include <hip/hip_fp16.h>

// LocalAttention: B=1, H=8, S=2048, D=64, window +/-64 (129 positions), fp32 io.
// R6 split-k MFMA structure + async fp32 staging via global_load_lds.
// 256 blocks (1/CU), 512 threads (8 waves): t = w&3 (q-tile), half = w>>2
// (chunks 0-2 / 3-5 of 192 staged rows).
// Staging: 12x global_load_lds(16B)/thread of raw fp32 K,V; source chunk index
// XOR-swizzled (c ^ ((row&7)<<1), even => 32B pairs stay adjacent); OOB rows
// CLAMPED (finite values; masks reproduce reference clip+mask semantics).
// K fragments read fp32 from LDS + cvt in-loop. V converted once LDS->LDS into
// the verified f16 V^T (384B stride + 16B-unit XOR swizzle). Main loop/combine
// identical to R6. h = blockIdx.x & 7 keeps each head on one XCD's L2.

#define SEQ 2048
#define QB 64
#define ROWS 192
#define PSTR 40          // P strip stride in halfs (80 B)

typedef _Float16 f16x8 __attribute__((ext_vector_type(8)));
typedef float    f32x4 __attribute__((ext_vector_type(4)));

#define GLOAD_LDS16(gsrc, ldst)                                              \
    __builtin_amdgcn_global_load_lds(                                        \
        (const __attribute__((address_space(1))) unsigned int*)(gsrc),       \
        (__attribute__((address_space(3))) unsigned int*)(ldst), 16, 0, 0)

__global__ __launch_bounds__(512) void local_attn(
    const float* __restrict__ q,
    const float* __restrict__ k,
    const float* __restrict__ v,
    float* __restrict__ out)
{
    // LDS layout (153600 B total):
    //   KF  [0      .. 49152)  K fp32, [192 rows][16 chunks of 16B], src-swizzled
    //   VF  [49152  .. 98304)  V fp32, same layout
    //   VtB [98304  ..122880)  V^T f16, 64 dims x 384 B, 16B-unit XOR swizzle
    //   Pm  [122880 ..133120)  8 waves x 16 x PSTR halfs
    //   Cmb [133120 ..153600)  4 tiles x 64 lanes x 20 f32
    __shared__ __align__(16) unsigned char LDS[153600];
    unsigned char* KF   = LDS;
    unsigned char* VF   = LDS + 49152;
    unsigned char* VtB  = LDS + 98304;
    _Float16*      PmB  = (_Float16*)(LDS + 122880);
    float*         CmbB = (float*)(LDS + 133120);

    const int tid  = threadIdx.x;
    const int lane = tid & 63;
    const int w    = tid >> 6;           // 0..7
    const int t    = w & 3;              // q-tile 0..3
    const int half = w >> 2;             // 0: chunks 0-2, 1: chunks 3-5
    const int l15  = lane & 15;
    const int l4   = lane >> 4;
    const int bx   = blockIdx.x;
    const int h     = bx & 7;            // head == XCD (round-robin dispatch)
    const int qbase = (bx >> 3) * QB;

    const float* qh = q + (size_t)h * SEQ * 64;
    const float* kh = k + (size_t)h * SEQ * 64;
    const float* vh = v + (size_t)h * SEQ * 64;

    // ---- Q loads first (ready at vmcnt(12) while staging drains)
    const float* qrow = qh + (size_t)(qbase + t * 16 + l15) * 64 + l4 * 8;
    float4 q0 = *(const float4*)(qrow);
    float4 q1 = *(const float4*)(qrow + 4);
    float4 q2 = *(const float4*)(qrow + 32);
    float4 q3 = *(const float4*)(qrow + 36);

    // ---- async stage K,V fp32 -> LDS (source chunk-swizzled, rows clamped)
    #pragma unroll
    for (int j = 0; j < 6; ++j) {
        const int s    = tid + j * 512;      // slot 0..3071
        const int row  = s >> 4;             // staged row 0..191
        const int cpos = s & 15;             // 16B chunk position in LDS row
        const int gch  = cpos ^ ((row & 7) << 1);   // global chunk (involution)
        int g = qbase - 64 + row;
        g = g < 0 ? 0 : (g > SEQ - 1 ? SEQ - 1 : g);
        const size_t goff = (size_t)g * 64 + gch * 4;
        GLOAD_LDS16(kh + goff, KF + s * 16);
        GLOAD_LDS16(vh + goff, VF + s * 16);
    }

    // ---- pack Q A-fragments (1/sqrt(64)=0.125 folded in) while loads fly
    union uf { f16x8 v; _Float16 hh[8]; };
    uf A0, A1;
    A0.hh[0] = (_Float16)(q0.x * 0.125f); A0.hh[1] = (_Float16)(q0.y * 0.125f);
    A0.hh[2] = (_Float16)(q0.z * 0.125f); A0.hh[3] = (_Float16)(q0.w * 0.125f);
    A0.hh[4] = (_Float16)(q1.x * 0.125f); A0.hh[5] = (_Float16)(q1.y * 0.125f);
    A0.hh[6] = (_Float16)(q1.z * 0.125f); A0.hh[7] = (_Float16)(q1.w * 0.125f);
    A1.hh[0] = (_Float16)(q2.x * 0.125f); A1.hh[1] = (_Float16)(q2.y * 0.125f);
    A1.hh[2] = (_Float16)(q2.z * 0.125f); A1.hh[3] = (_Float16)(q2.w * 0.125f);
    A1.hh[4] = (_Float16)(q3.x * 0.125f); A1.hh[5] = (_Float16)(q3.y * 0.125f);
    A1.hh[6] = (_Float16)(q3.z * 0.125f); A1.hh[7] = (_Float16)(q3.w * 0.125f);

    asm volatile("s_waitcnt vmcnt(0)" ::: "memory");
    __syncthreads();

    // ---- convert V: fp32 LDS -> f16 V^T (separate region, no alias)
    {
        const int d0 = (tid & 15) * 4;       // 4 dims per thread
        const int rr = (tid >> 4) * 6;       // 6 rows per thread
        #pragma unroll
        for (int i = 0; i < 6; ++i) {
            const int r    = rr + i;
            const int cpos = (tid & 15) ^ ((r & 7) << 1);
            f32x4 tmp = *(const f32x4*)(VF + r * 256 + cpos * 16);
            #pragma unroll
            for (int i2 = 0; i2 < 4; ++i2) {
                const int d = d0 + i2;
                const int u = (r >> 3) ^ (d & 7);
                *(_Float16*)&VtB[d * 384 + (u << 4) + (r & 7) * 2] =
                    (_Float16)tmp[i2];
            }
        }
    }
    __syncthreads();

    // ---- main loop: wave-private, 3 chunks per wave
    _Float16* Pw = PmB + w * 16 * PSTR;
    float rsum[4] = {0.f, 0.f, 0.f, 0.f};
    f32x4 o[4];
    #pragma unroll
    for (int dt = 0; dt < 4; ++dt) o[dt] = (f32x4){0.f, 0.f, 0.f, 0.f};

    #pragma unroll
    for (int c = 0; c < 3; ++c) {
        const int r0 = (half * 3 + c) * 32;

        // QK^T for this 32-row chunk: 2 tiles; B-frags from fp32 KF + cvt
        #pragma unroll
        for (int t2 = 0; t2 < 2; ++t2) {
            const int r = r0 + t2 * 16 + l15;          // staged row (C col)
            const int x = (r & 7) << 1;
            const unsigned a0 = r * 256 + ((unsigned)((l4 * 2) ^ x) << 4);
            const unsigned a1 = r * 256 + ((unsigned)((l4 * 2 + 8) ^ x) << 4);
            f32x4 k0 = *(const f32x4*)(KF + a0);
            f32x4 k1 = *(const f32x4*)(KF + a0 + 16);
            f32x4 k2 = *(const f32x4*)(KF + a1);
            f32x4 k3 = *(const f32x4*)(KF + a1 + 16);
            uf b0, b1;
            #pragma unroll
            for (int j = 0; j < 4; ++j) {
                b0.hh[j]     = (_Float16)k0[j];
                b0.hh[j + 4] = (_Float16)k1[j];
                b1.hh[j]     = (_Float16)k2[j];
                b1.hh[j + 4] = (_Float16)k3[j];
            }
            f32x4 cacc = {0.f, 0.f, 0.f, 0.f};
            cacc = __builtin_amdgcn_mfma_f32_16x16x32_f16(A0.v, b0.v, cacc, 0, 0, 0);
            cacc = __builtin_amdgcn_mfma_f32_16x16x32_f16(A1.v, b1.v, cacc, 0, 0, 0);
            const int g  = qbase - 64 + r;
            const bool gv = (g >= 0) & (g < SEQ);
            #pragma unroll
            for (int j = 0; j < 4; ++j) {
                const int qg = qbase + t * 16 + l4 * 4 + j;   // global query (C row)
                const bool valid = gv && (g >= qg - 64) && (g <= qg + 64);
                const float e = valid ? __expf(cacc[j]) : 0.f;
                rsum[j] += e;
                Pw[(l4 * 4 + j) * PSTR + t2 * 16 + l15] = (_Float16)e;
            }
        }

        // same-wave DS order; drain so P reads see the writes
        asm volatile("s_waitcnt lgkmcnt(0)" ::: "memory");

        // PV: A = P chunk (lane l15 = query), B = V^T (lane l15 = dim)
        f16x8 a = *(const f16x8*)&Pw[l15 * PSTR + l4 * 8];
        #pragma unroll
        for (int dt = 0; dt < 4; ++dt) {
            const int dim = dt * 16 + l15;
            const int u   = ((r0 + l4 * 8) >> 3) ^ (dim & 7);
            f16x8 bb = *(const f16x8*)&VtB[dim * 384 + (u << 4)];
            o[dt] = __builtin_amdgcn_mfma_f32_16x16x32_f16(a, bb, o[dt], 0, 0, 0);
        }
    }

    // ---- split-k combine: half-1 waves publish partials; half-0 waves merge
    float* Cl = CmbB + (t * 64 + lane) * 20;
    if (half == 1) {
        #pragma unroll
        for (int dt = 0; dt < 4; ++dt)
            *(f32x4*)(Cl + dt * 4) = o[dt];
        f32x4 pr = {rsum[0], rsum[1], rsum[2], rsum[3]};
        *(f32x4*)(Cl + 16) = pr;
    }
    __syncthreads();
    if (half == 0) {
        #pragma unroll
        for (int dt = 0; dt < 4; ++dt) {
            f32x4 p = *(const f32x4*)(Cl + dt * 4);
            o[dt] += p;
        }
        f32x4 pr = *(const f32x4*)(Cl + 16);

        #pragma unroll
        for (int j = 0; j < 4; ++j) {
            float l = rsum[j] + pr[j];
            l += __shfl_xor(l, 1, 64);
            l += __shfl_xor(l, 2, 64);
            l += __shfl_xor(l, 4, 64);
            l += __shfl_xor(l, 8, 64);
            const float inv = 1.0f / l;
            const int qg = qbase + t * 16 + l4 * 4 + j;
            #pragma unroll
            for (int dt = 0; dt < 4; ++dt)
                out[((size_t)h * SEQ + qg) * 64 + dt * 16 + l15] = o[dt][j] * inv;
        }
    }
}

extern "C" void kernel_launch(void* const* d_in, const int* in_sizes, int n_in,
                              void* d_out, int out_size, void* d_ws, size_t ws_size,
                              hipStream_t stream)
{
    const float* q = (const float*)d_in[0];
    const float* k = (const float*)d_in[1];
    const float* v = (const float*)d_in[2];
    float* out = (float*)d_out;

    // 256 blocks = 1 per CU; low 3 bits = head -> one head per XCD (L2 locality)
    local_attn<<<256, 512, 0, stream>>>(q, k, v, out);
}